// Round 3
// baseline (609.773 us; speedup 1.0000x reference)
//
#include <hip/hip_runtime.h>

#define CC 64
#define HH 128
#define WW 128
#define HWS (HH * WW)
#define NG 4

// Fold {grid_sample 2 corners (1-t, t; zeros padding)} x {2x bilinear
// upsample taps, align_corners=False} into <=3 consecutive source taps
// starting at `base`. Branchless: no runtime-indexed local arrays (rule #20).
__device__ __forceinline__ void make_taps(float gp, int n, int half, int& base,
                                          float& w0o, float& w1o, float& w2o) {
  float w0 = 0.0f, w1 = 0.0f, w2 = 0.0f;
  float f = floorf(gp);
  int x0 = (int)f;
  float t = gp - f;
  int b = 0;
#pragma unroll
  for (int k = 0; k < 2; ++k) {
    int xc = x0 + k;
    float cw = k ? t : 1.0f - t;
    if (xc < 0 || xc >= n) cw = 0.0f;      // zeros-padding validity
    int xcc = min(max(xc, 0), n - 1);      // safe index (weight 0 if clipped)
    int u = half * n + xcc;                // index in upsampled axis
    float src = fmaxf((float)u * 0.5f - 0.25f, 0.0f);  // (u+0.5)/2 - 0.5
    float sf = floorf(src);
    int i0 = (int)sf;
    float tu = src - sf;
    int i1 = min(i0 + 1, n - 1);
    if (k == 0) b = i0;                    // min tap index (i0 is monotone in k)
    int s0 = i0 - b;                       // 0 or 1
    int s1 = i1 - b;                       // 0, 1, or 2
    float a0 = cw * (1.0f - tu);
    float a1 = cw * tu;
    w0 += (s0 == 0) ? a0 : 0.0f;
    w1 += (s0 == 1) ? a0 : 0.0f;
    w0 += (s1 == 0) ? a1 : 0.0f;
    w1 += (s1 == 1) ? a1 : 0.0f;
    w2 += (s1 == 2) ? a1 : 0.0f;
  }
  base = b;
  w0o = w0; w1o = w1; w2o = w2;
}

__global__ __launch_bounds__(256, 4) void dysample_fused(
    const float* __restrict__ x,
    const float* __restrict__ w_off, const float* __restrict__ b_off,
    const float* __restrict__ w_mask, const float* __restrict__ b_mask,
    float* __restrict__ out, int npix) {
  // stage conv weights transposed: wt[c][d], d in [0,12): 0-7 offset, 8-11 mask
  __shared__ float wt[CC * 12];
  for (int idx = threadIdx.x; idx < CC * 12; idx += 256) {
    int c = idx / 12, d = idx - c * 12;
    wt[idx] = (d < 8) ? w_off[d * CC + c] : w_mask[(d - 8) * CC + c];
  }
  __syncthreads();

  int pix = blockIdx.x * 256 + threadIdx.x;
  if (pix >= npix) return;
  int b = pix >> 14;            // / (128*128)
  int ij = pix & (HWS - 1);
  int i = ij >> 7, j = ij & (WW - 1);

  const float* __restrict__ xp = x + (size_t)b * CC * HWS;

  // 1x1 convs: 8 offset channels + 4 mask channels
  float a12[12];
#pragma unroll
  for (int d = 0; d < 12; ++d) a12[d] = (d < 8) ? b_off[d] : b_mask[d - 8];

#pragma unroll 4
  for (int c = 0; c < CC; ++c) {
    float xv = xp[c * HWS + ij];
    const float4 w0 = *reinterpret_cast<const float4*>(&wt[c * 12 + 0]);
    const float4 w1 = *reinterpret_cast<const float4*>(&wt[c * 12 + 4]);
    const float4 w2 = *reinterpret_cast<const float4*>(&wt[c * 12 + 8]);
    a12[0]  = fmaf(w0.x, xv, a12[0]);
    a12[1]  = fmaf(w0.y, xv, a12[1]);
    a12[2]  = fmaf(w0.z, xv, a12[2]);
    a12[3]  = fmaf(w0.w, xv, a12[3]);
    a12[4]  = fmaf(w1.x, xv, a12[4]);
    a12[5]  = fmaf(w1.y, xv, a12[5]);
    a12[6]  = fmaf(w1.z, xv, a12[6]);
    a12[7]  = fmaf(w1.w, xv, a12[7]);
    a12[8]  = fmaf(w2.x, xv, a12[8]);
    a12[9]  = fmaf(w2.y, xv, a12[9]);
    a12[10] = fmaf(w2.z, xv, a12[10]);
    a12[11] = fmaf(w2.w, xv, a12[11]);
  }

  // compact per-group geometry: col/row bases + separable weights (mask folded
  // into wy). 8 regs per group; all array indices static after unroll.
  int cbs[NG], rbs[NG];
  float wxs[NG][3], wys[NG][3];
#pragma unroll
  for (int g = 0; g < NG; ++g) {
    int sy = g >> 1, sx = g & 1;
    float mg = 1.0f / (1.0f + __expf(-a12[8 + g]));  // sigmoid(mask)
    float gxp = (float)j + a12[2 * g]     - 0.5f;    // pixel-space sample x
    float gyp = (float)i + a12[2 * g + 1] - 0.5f;    // pixel-space sample y
    make_taps(gxp, WW, sx, cbs[g], wxs[g][0], wxs[g][1], wxs[g][2]);
    float wy0, wy1, wy2;
    make_taps(gyp, HH, sy, rbs[g], wy0, wy1, wy2);
    wys[g][0] = wy0 * mg; wys[g][1] = wy1 * mg; wys[g][2] = wy2 * mg;
  }

  // channel-blocked stencil: 4 blocks of 16 channels; per (block, group)
  // 144 independent gathers into 16 static accumulators.
  float* __restrict__ op = out + (size_t)b * CC * HWS + ij;
  for (int blk = 0; blk < 4; ++blk) {
    const float* __restrict__ xb = xp + blk * 16 * HWS;
    float acc[16];
#pragma unroll
    for (int c = 0; c < 16; ++c) acc[c] = 0.0f;
#pragma unroll
    for (int g = 0; g < NG; ++g) {
      int o9[9];
      float w9v[9];
#pragma unroll
      for (int dy = 0; dy < 3; ++dy) {
        int r = min(rbs[g] + dy, HH - 1) * WW;
        float wyv = wys[g][dy];
#pragma unroll
        for (int dx = 0; dx < 3; ++dx) {
          o9[dy * 3 + dx] = r + min(cbs[g] + dx, WW - 1);
          w9v[dy * 3 + dx] = wyv * wxs[g][dx];
        }
      }
#pragma unroll
      for (int c = 0; c < 16; ++c) {
#pragma unroll
        for (int k = 0; k < 9; ++k) {
          acc[c] = fmaf(w9v[k], xb[c * HWS + o9[k]], acc[c]);
        }
      }
    }
    float* __restrict__ ob = op + blk * 16 * HWS;
#pragma unroll
    for (int c = 0; c < 16; ++c) ob[c * HWS] = acc[c];
  }
}

extern "C" void kernel_launch(void* const* d_in, const int* in_sizes, int n_in,
                              void* d_out, int out_size, void* d_ws, size_t ws_size,
                              hipStream_t stream) {
  const float* x      = (const float*)d_in[0];
  const float* w_off  = (const float*)d_in[1];
  const float* b_off  = (const float*)d_in[2];
  const float* w_mask = (const float*)d_in[3];
  const float* b_mask = (const float*)d_in[4];
  float* out = (float*)d_out;

  int B = in_sizes[0] / (CC * HWS);
  int npix = B * HWS;
  int nblk = (npix + 255) / 256;
  hipLaunchKernelGGL(dysample_fused, dim3(nblk), dim3(256), 0, stream,
                     x, w_off, b_off, w_mask, b_mask, out, npix);
}

// Round 4
// 330.623 us; speedup vs baseline: 1.8443x; 1.8443x over previous
//
#include <hip/hip_runtime.h>

#define CC 64
#define HH 128
#define WW 128
#define HWS (HH * WW)
#define NG 4

// Fold {grid_sample 2 corners (1-t, t; zeros padding)} x {2x bilinear
// upsample taps, align_corners=False} into <=3 consecutive source taps
// starting at `base`. Branchless, no runtime-indexed locals (rule #20).
__device__ __forceinline__ void make_taps(float gp, int n, int half, int& base,
                                          float& w0o, float& w1o, float& w2o) {
  float w0 = 0.0f, w1 = 0.0f, w2 = 0.0f;
  float f = floorf(gp);
  int x0 = (int)f;
  float t = gp - f;
  int b = 0;
#pragma unroll
  for (int k = 0; k < 2; ++k) {
    int xc = x0 + k;
    float cw = k ? t : 1.0f - t;
    if (xc < 0 || xc >= n) cw = 0.0f;      // zeros-padding validity
    int xcc = min(max(xc, 0), n - 1);      // safe index (weight 0 if clipped)
    int u = half * n + xcc;                // index in upsampled axis
    float src = fmaxf((float)u * 0.5f - 0.25f, 0.0f);  // (u+0.5)/2 - 0.5
    float sf = floorf(src);
    int i0 = (int)sf;
    float tu = src - sf;
    int i1 = min(i0 + 1, n - 1);
    if (k == 0) b = i0;                    // min tap index (i0 monotone in k)
    int s0 = i0 - b;                       // 0 or 1
    int s1 = i1 - b;                       // 0, 1, or 2
    float a0 = cw * (1.0f - tu);
    float a1 = cw * tu;
    w0 += (s0 == 0) ? a0 : 0.0f;
    w1 += (s0 == 1) ? a0 : 0.0f;
    w0 += (s1 == 0) ? a1 : 0.0f;
    w1 += (s1 == 1) ? a1 : 0.0f;
    w2 += (s1 == 2) ? a1 : 0.0f;
  }
  base = b;
  w0o = w0; w1o = w1; w2o = w2;
}

__global__ __launch_bounds__(256) void dysample_fused(
    const float* __restrict__ x,
    const float* __restrict__ w_off, const float* __restrict__ b_off,
    const float* __restrict__ w_mask, const float* __restrict__ b_mask,
    float* __restrict__ out, int npix) {
  // stage conv weights transposed: wt[c][d], d in [0,12): 0-7 offset, 8-11 mask
  __shared__ float wt[CC * 12];
  for (int idx = threadIdx.x; idx < CC * 12; idx += 256) {
    int c = idx / 12, d = idx - c * 12;
    wt[idx] = (d < 8) ? w_off[d * CC + c] : w_mask[(d - 8) * CC + c];
  }
  __syncthreads();

  // XCD-aware bijective swizzle (nwg % 8 == 0 here): each XCD gets a
  // contiguous chunk so overlapping stencil windows stay in its L2.
  int nwg = gridDim.x;
  int bid = blockIdx.x;
  int swz = ((nwg & 7) == 0) ? ((bid & 7) * (nwg >> 3) + (bid >> 3)) : bid;

  int pix = swz * 256 + threadIdx.x;
  if (pix >= npix) return;
  int b = pix >> 14;            // / (128*128)
  int ij = pix & (HWS - 1);
  int i = ij >> 7, j = ij & (WW - 1);

  const float* __restrict__ xp = x + (size_t)b * CC * HWS;

  // 1x1 convs: 8 offset channels + 4 mask channels
  float a12[12];
#pragma unroll
  for (int d = 0; d < 12; ++d) a12[d] = (d < 8) ? b_off[d] : b_mask[d - 8];

#pragma unroll 4
  for (int c = 0; c < CC; ++c) {
    float xv = xp[c * HWS + ij];
    const float4 w0 = *reinterpret_cast<const float4*>(&wt[c * 12 + 0]);
    const float4 w1 = *reinterpret_cast<const float4*>(&wt[c * 12 + 4]);
    const float4 w2 = *reinterpret_cast<const float4*>(&wt[c * 12 + 8]);
    a12[0]  = fmaf(w0.x, xv, a12[0]);
    a12[1]  = fmaf(w0.y, xv, a12[1]);
    a12[2]  = fmaf(w0.z, xv, a12[2]);
    a12[3]  = fmaf(w0.w, xv, a12[3]);
    a12[4]  = fmaf(w1.x, xv, a12[4]);
    a12[5]  = fmaf(w1.y, xv, a12[5]);
    a12[6]  = fmaf(w1.z, xv, a12[6]);
    a12[7]  = fmaf(w1.w, xv, a12[7]);
    a12[8]  = fmaf(w2.x, xv, a12[8]);
    a12[9]  = fmaf(w2.y, xv, a12[9]);
    a12[10] = fmaf(w2.z, xv, a12[10]);
    a12[11] = fmaf(w2.w, xv, a12[11]);
  }

  // per-group separable geometry: 3 row offsets (pre-multiplied by WW),
  // 3 col offsets, 3+3 weights (mask folded into wy). All indices static.
  int ro[NG][3], co[NG][3];
  float wx[NG][3], wy[NG][3];
#pragma unroll
  for (int g = 0; g < NG; ++g) {
    int sy = g >> 1, sx = g & 1;
    float mg = 1.0f / (1.0f + __expf(-a12[8 + g]));  // sigmoid(mask)
    int cb, rb;
    float x0, x1, x2, y0, y1, y2;
    make_taps((float)j + a12[2 * g]     - 0.5f, WW, sx, cb, x0, x1, x2);
    make_taps((float)i + a12[2 * g + 1] - 0.5f, HH, sy, rb, y0, y1, y2);
    wx[g][0] = x0;      wx[g][1] = x1;      wx[g][2] = x2;
    wy[g][0] = y0 * mg; wy[g][1] = y1 * mg; wy[g][2] = y2 * mg;
#pragma unroll
    for (int d = 0; d < 3; ++d) {
      ro[g][d] = min(rb + d, HH - 1) * WW;
      co[g][d] = min(cb + d, WW - 1);
    }
  }

  // channel-blocked stencil: 4 blocks of 16 channels.
  float* __restrict__ op = out + (size_t)b * CC * HWS + ij;
  for (int blk = 0; blk < 4; ++blk) {
    const float* __restrict__ xb = xp + blk * 16 * HWS;
    float acc[16];
#pragma unroll
    for (int c = 0; c < 16; ++c) acc[c] = 0.0f;
#pragma unroll
    for (int g = 0; g < NG; ++g) {
      int o9[9];
      float w9[9];
#pragma unroll
      for (int dy = 0; dy < 3; ++dy) {
#pragma unroll
        for (int dx = 0; dx < 3; ++dx) {
          o9[dy * 3 + dx] = ro[g][dy] + co[g][dx];
          w9[dy * 3 + dx] = wy[g][dy] * wx[g][dx];
        }
      }
#pragma unroll
      for (int c = 0; c < 16; ++c) {
        const float* __restrict__ xc = xb + c * HWS;
#pragma unroll
        for (int k = 0; k < 9; ++k) {
          acc[c] = fmaf(w9[k], xc[o9[k]], acc[c]);
        }
      }
    }
#pragma unroll
    for (int c = 0; c < 16; ++c) op[(blk * 16 + c) * HWS] = acc[c];
  }
}

extern "C" void kernel_launch(void* const* d_in, const int* in_sizes, int n_in,
                              void* d_out, int out_size, void* d_ws, size_t ws_size,
                              hipStream_t stream) {
  const float* x      = (const float*)d_in[0];
  const float* w_off  = (const float*)d_in[1];
  const float* b_off  = (const float*)d_in[2];
  const float* w_mask = (const float*)d_in[3];
  const float* b_mask = (const float*)d_in[4];
  float* out = (float*)d_out;

  int B = in_sizes[0] / (CC * HWS);
  int npix = B * HWS;
  int nblk = (npix + 255) / 256;
  hipLaunchKernelGGL(dysample_fused, dim3(nblk), dim3(256), 0, stream,
                     x, w_off, b_off, w_mask, b_mask, out, npix);
}

// Round 5
// 136.248 us; speedup vs baseline: 4.4755x; 2.4266x over previous
//
#include <hip/hip_runtime.h>

#define CC 64
#define HH 128
#define WW 128
#define HWS (HH * WW)
#define NG 4

// Fold {grid_sample 2 corners (1-t, t; zeros padding)} x {2x bilinear
// upsample taps, align_corners=False} into <=3 consecutive source taps
// starting at `base`. Branchless, no runtime-indexed locals.
__device__ __forceinline__ void make_taps(float gp, int n, int half, int& base,
                                          float& w0o, float& w1o, float& w2o) {
  float w0 = 0.0f, w1 = 0.0f, w2 = 0.0f;
  float f = floorf(gp);
  int x0 = (int)f;
  float t = gp - f;
  int b = 0;
#pragma unroll
  for (int k = 0; k < 2; ++k) {
    int xc = x0 + k;
    float cw = k ? t : 1.0f - t;
    if (xc < 0 || xc >= n) cw = 0.0f;
    int xcc = min(max(xc, 0), n - 1);
    int u = half * n + xcc;
    float src = fmaxf((float)u * 0.5f - 0.25f, 0.0f);
    float sf = floorf(src);
    int i0 = (int)sf;
    float tu = src - sf;
    int i1 = min(i0 + 1, n - 1);
    if (k == 0) b = i0;
    int s0 = i0 - b;
    int s1 = i1 - b;
    float a0 = cw * (1.0f - tu);
    float a1 = cw * tu;
    w0 += (s0 == 0) ? a0 : 0.0f;
    w1 += (s0 == 1) ? a0 : 0.0f;
    w0 += (s1 == 0) ? a1 : 0.0f;
    w1 += (s1 == 1) ? a1 : 0.0f;
    w2 += (s1 == 2) ? a1 : 0.0f;
  }
  base = b;
  w0o = w0; w1o = w1; w2o = w2;
}

// ---------- Kernel A: 1x1 conv (a12) + NCHW->NHWC transpose (xT) ----------
__global__ __launch_bounds__(256) void prep_conv_transpose(
    const float* __restrict__ x,
    const float* __restrict__ w_off, const float* __restrict__ b_off,
    const float* __restrict__ w_mask, const float* __restrict__ b_mask,
    float* __restrict__ xT, float* __restrict__ a12o, int npix) {
  __shared__ float wt[CC * 12];
  __shared__ float tile[16][68];   // [pixel][channel], padded
  int t = threadIdx.x;
  for (int idx = t; idx < CC * 12; idx += 256) {
    int c = idx / 12, d = idx - c * 12;
    wt[idx] = (d < 8) ? w_off[d * CC + c] : w_mask[(d - 8) * CC + c];
  }
  __syncthreads();

  int pix0 = blockIdx.x * 256;
  int pix = pix0 + t;
  int b = pix >> 14;
  int ij = pix & (HWS - 1);
  const float* __restrict__ xp = x + (size_t)b * CC * HWS;

  float a12[12];
#pragma unroll
  for (int d = 0; d < 12; ++d) a12[d] = (d < 8) ? b_off[d] : b_mask[d - 8];
#pragma unroll 4
  for (int c = 0; c < CC; ++c) {
    float xv = xp[c * HWS + ij];
    const float4 w0 = *reinterpret_cast<const float4*>(&wt[c * 12 + 0]);
    const float4 w1 = *reinterpret_cast<const float4*>(&wt[c * 12 + 4]);
    const float4 w2 = *reinterpret_cast<const float4*>(&wt[c * 12 + 8]);
    a12[0]  = fmaf(w0.x, xv, a12[0]);   a12[1]  = fmaf(w0.y, xv, a12[1]);
    a12[2]  = fmaf(w0.z, xv, a12[2]);   a12[3]  = fmaf(w0.w, xv, a12[3]);
    a12[4]  = fmaf(w1.x, xv, a12[4]);   a12[5]  = fmaf(w1.y, xv, a12[5]);
    a12[6]  = fmaf(w1.z, xv, a12[6]);   a12[7]  = fmaf(w1.w, xv, a12[7]);
    a12[8]  = fmaf(w2.x, xv, a12[8]);   a12[9]  = fmaf(w2.y, xv, a12[9]);
    a12[10] = fmaf(w2.z, xv, a12[10]);  a12[11] = fmaf(w2.w, xv, a12[11]);
  }
  float4* ao = reinterpret_cast<float4*>(a12o + (size_t)pix * 12);  // 48B stride, 16B aligned
  ao[0] = make_float4(a12[0], a12[1], a12[2], a12[3]);
  ao[1] = make_float4(a12[4], a12[5], a12[6], a12[7]);
  ao[2] = make_float4(a12[8], a12[9], a12[10], a12[11]);

  // transpose 256 pixels in 16 chunks of (16 pixels x 64 channels)
  for (int ch = 0; ch < 16; ++ch) {
    int p0 = pix0 + ch * 16;                 // global linear pixel base
    int bb = p0 >> 14;
    int ij0 = p0 & (HWS - 1);
    const float* __restrict__ xq = x + (size_t)bb * CC * HWS + ij0;
    float v[4];
#pragma unroll
    for (int k = 0; k < 4; ++k) {            // coalesced plane reads (hot in L2/L3)
      int idx = k * 256 + t;
      int c = idx >> 4, p = idx & 15;
      v[k] = xq[c * HWS + p];
    }
    __syncthreads();
#pragma unroll
    for (int k = 0; k < 4; ++k) {
      int idx = k * 256 + t;
      int c = idx >> 4, p = idx & 15;
      tile[p][c] = v[k];
    }
    __syncthreads();
    // lane t -> pixel t>>4, channel-quad t&15: 1KB contiguous per wave
    float4 o = *reinterpret_cast<float4*>(&tile[t >> 4][(t & 15) * 4]);
    *reinterpret_cast<float4*>(xT + ((size_t)p0 + (t >> 4)) * 64 + (t & 15) * 4) = o;
  }
}

// ---------- Kernel B: NHWC gather-sampler ----------
__global__ __launch_bounds__(256) void sample_nhwc(
    const float* __restrict__ xT, const float* __restrict__ a12o,
    float* __restrict__ out, int npix) {
  __shared__ float obuf[16][68];   // [pixel][channel], padded
  int t = threadIdx.x;
  int p = t >> 4;                  // pixel-in-block 0..15
  int q = t & 15;                  // channel quad 0..15

  // XCD-aware bijective swizzle (nwg % 8 == 0 here)
  int nwg = gridDim.x;
  int bid = blockIdx.x;
  int swz = ((nwg & 7) == 0) ? ((bid & 7) * (nwg >> 3) + (bid >> 3)) : bid;

  int pix = swz * 16 + p;
  int b = pix >> 14;
  int ij = pix & (HWS - 1);
  int i = ij >> 7, j = ij & (WW - 1);

  const float4* __restrict__ ap =
      reinterpret_cast<const float4*>(a12o + (size_t)pix * 12);
  float4 A0 = ap[0], A1 = ap[1], A2 = ap[2];
  float a12[12] = {A0.x, A0.y, A0.z, A0.w, A1.x, A1.y, A1.z, A1.w,
                   A2.x, A2.y, A2.z, A2.w};

  // per-group separable geometry (redundant across the 16-lane group; SIMD-free)
  int ro[NG][3], co[NG][3];
  float wx[NG][3], wy[NG][3];
#pragma unroll
  for (int g = 0; g < NG; ++g) {
    int sy = g >> 1, sx = g & 1;
    float mg = 1.0f / (1.0f + __expf(-a12[8 + g]));
    int cb, rb;
    float x0, x1, x2, y0, y1, y2;
    make_taps((float)j + a12[2 * g]     - 0.5f, WW, sx, cb, x0, x1, x2);
    make_taps((float)i + a12[2 * g + 1] - 0.5f, HH, sy, rb, y0, y1, y2);
    wx[g][0] = x0;      wx[g][1] = x1;      wx[g][2] = x2;
    wy[g][0] = y0 * mg; wy[g][1] = y1 * mg; wy[g][2] = y2 * mg;
#pragma unroll
    for (int d = 0; d < 3; ++d) {
      ro[g][d] = min(rb + d, HH - 1) * WW;
      co[g][d] = min(cb + d, WW - 1);
    }
  }

  const float* __restrict__ xb = xT + ((size_t)b * HWS) * 64 + q * 4;
  float4 acc = make_float4(0.f, 0.f, 0.f, 0.f);
#pragma unroll
  for (int g = 0; g < NG; ++g) {
#pragma unroll
    for (int dy = 0; dy < 3; ++dy) {
#pragma unroll
      for (int dx = 0; dx < 3; ++dx) {
        float w = wy[g][dy] * wx[g][dx];
        const float4 v = *reinterpret_cast<const float4*>(
            xb + (size_t)(ro[g][dy] + co[g][dx]) * 64);
        acc.x = fmaf(w, v.x, acc.x);
        acc.y = fmaf(w, v.y, acc.y);
        acc.z = fmaf(w, v.z, acc.z);
        acc.w = fmaf(w, v.w, acc.w);
      }
    }
  }

  *reinterpret_cast<float4*>(&obuf[p][q * 4]) = acc;
  __syncthreads();

  // coalesced NCHW stores: 4 dwords/thread, 64B-line granularity
  int ij0 = (swz * 16) & (HWS - 1);
  float* __restrict__ op = out + (size_t)b * CC * HWS + ij0;
#pragma unroll
  for (int k = 0; k < 4; ++k) {
    int idx = k * 256 + t;
    int c = idx >> 4, jj = idx & 15;
    op[(size_t)c * HWS + jj] = obuf[jj][c];
  }
}

// ---------- Fallback: round-4 fused kernel (used if ws too small) ----------
__global__ __launch_bounds__(256) void dysample_fused(
    const float* __restrict__ x,
    const float* __restrict__ w_off, const float* __restrict__ b_off,
    const float* __restrict__ w_mask, const float* __restrict__ b_mask,
    float* __restrict__ out, int npix) {
  __shared__ float wt[CC * 12];
  for (int idx = threadIdx.x; idx < CC * 12; idx += 256) {
    int c = idx / 12, d = idx - c * 12;
    wt[idx] = (d < 8) ? w_off[d * CC + c] : w_mask[(d - 8) * CC + c];
  }
  __syncthreads();
  int nwg = gridDim.x;
  int bid = blockIdx.x;
  int swz = ((nwg & 7) == 0) ? ((bid & 7) * (nwg >> 3) + (bid >> 3)) : bid;
  int pix = swz * 256 + threadIdx.x;
  if (pix >= npix) return;
  int b = pix >> 14;
  int ij = pix & (HWS - 1);
  int i = ij >> 7, j = ij & (WW - 1);
  const float* __restrict__ xp = x + (size_t)b * CC * HWS;
  float a12[12];
#pragma unroll
  for (int d = 0; d < 12; ++d) a12[d] = (d < 8) ? b_off[d] : b_mask[d - 8];
#pragma unroll 4
  for (int c = 0; c < CC; ++c) {
    float xv = xp[c * HWS + ij];
    const float4 w0 = *reinterpret_cast<const float4*>(&wt[c * 12 + 0]);
    const float4 w1 = *reinterpret_cast<const float4*>(&wt[c * 12 + 4]);
    const float4 w2 = *reinterpret_cast<const float4*>(&wt[c * 12 + 8]);
    a12[0]  = fmaf(w0.x, xv, a12[0]);   a12[1]  = fmaf(w0.y, xv, a12[1]);
    a12[2]  = fmaf(w0.z, xv, a12[2]);   a12[3]  = fmaf(w0.w, xv, a12[3]);
    a12[4]  = fmaf(w1.x, xv, a12[4]);   a12[5]  = fmaf(w1.y, xv, a12[5]);
    a12[6]  = fmaf(w1.z, xv, a12[6]);   a12[7]  = fmaf(w1.w, xv, a12[7]);
    a12[8]  = fmaf(w2.x, xv, a12[8]);   a12[9]  = fmaf(w2.y, xv, a12[9]);
    a12[10] = fmaf(w2.z, xv, a12[10]);  a12[11] = fmaf(w2.w, xv, a12[11]);
  }
  int ro[NG][3], co[NG][3];
  float wx[NG][3], wy[NG][3];
#pragma unroll
  for (int g = 0; g < NG; ++g) {
    int sy = g >> 1, sx = g & 1;
    float mg = 1.0f / (1.0f + __expf(-a12[8 + g]));
    int cb, rb;
    float x0, x1, x2, y0, y1, y2;
    make_taps((float)j + a12[2 * g]     - 0.5f, WW, sx, cb, x0, x1, x2);
    make_taps((float)i + a12[2 * g + 1] - 0.5f, HH, sy, rb, y0, y1, y2);
    wx[g][0] = x0;      wx[g][1] = x1;      wx[g][2] = x2;
    wy[g][0] = y0 * mg; wy[g][1] = y1 * mg; wy[g][2] = y2 * mg;
#pragma unroll
    for (int d = 0; d < 3; ++d) {
      ro[g][d] = min(rb + d, HH - 1) * WW;
      co[g][d] = min(cb + d, WW - 1);
    }
  }
  float* __restrict__ op = out + (size_t)b * CC * HWS + ij;
  for (int blk = 0; blk < 4; ++blk) {
    const float* __restrict__ xb = xp + blk * 16 * HWS;
    float acc[16];
#pragma unroll
    for (int c = 0; c < 16; ++c) acc[c] = 0.0f;
#pragma unroll
    for (int g = 0; g < NG; ++g) {
      int o9[9];
      float w9[9];
#pragma unroll
      for (int dy = 0; dy < 3; ++dy) {
#pragma unroll
        for (int dx = 0; dx < 3; ++dx) {
          o9[dy * 3 + dx] = ro[g][dy] + co[g][dx];
          w9[dy * 3 + dx] = wy[g][dy] * wx[g][dx];
        }
      }
#pragma unroll
      for (int c = 0; c < 16; ++c) {
        const float* __restrict__ xc = xb + c * HWS;
#pragma unroll
        for (int k = 0; k < 9; ++k) acc[c] = fmaf(w9[k], xc[o9[k]], acc[c]);
      }
    }
#pragma unroll
    for (int c = 0; c < 16; ++c) op[(blk * 16 + c) * HWS] = acc[c];
  }
}

extern "C" void kernel_launch(void* const* d_in, const int* in_sizes, int n_in,
                              void* d_out, int out_size, void* d_ws, size_t ws_size,
                              hipStream_t stream) {
  const float* x      = (const float*)d_in[0];
  const float* w_off  = (const float*)d_in[1];
  const float* b_off  = (const float*)d_in[2];
  const float* w_mask = (const float*)d_in[3];
  const float* b_mask = (const float*)d_in[4];
  float* out = (float*)d_out;

  int B = in_sizes[0] / (CC * HWS);
  int npix = B * HWS;
  size_t need = (size_t)npix * 64 * 4 + (size_t)npix * 12 * 4;  // xT + a12

  if (ws_size >= need && (npix & 255) == 0) {
    float* xT   = (float*)d_ws;
    float* a12o = xT + (size_t)npix * 64;
    hipLaunchKernelGGL(prep_conv_transpose, dim3(npix / 256), dim3(256), 0,
                       stream, x, w_off, b_off, w_mask, b_mask, xT, a12o, npix);
    hipLaunchKernelGGL(sample_nhwc, dim3(npix / 16), dim3(256), 0, stream,
                       xT, a12o, out, npix);
  } else {
    int nblk = (npix + 255) / 256;
    hipLaunchKernelGGL(dysample_fused, dim3(nblk), dim3(256), 0, stream,
                       x, w_off, b_off, w_mask, b_mask, out, npix);
  }
}

// Round 6
// 92.992 us; speedup vs baseline: 6.5573x; 1.4652x over previous
//
#include <hip/hip_runtime.h>
#include <hip/hip_fp16.h>

#define CC 64
#define HH 128
#define WW 128
#define HWS (HH * WW)
#define NG 4

// Fold {grid_sample 2 corners (1-t, t; zeros padding)} x {2x bilinear
// upsample taps, align_corners=False} into <=3 consecutive source taps
// starting at `base`. Branchless, no runtime-indexed locals.
__device__ __forceinline__ void make_taps(float gp, int n, int half, int& base,
                                          float& w0o, float& w1o, float& w2o) {
  float w0 = 0.0f, w1 = 0.0f, w2 = 0.0f;
  float f = floorf(gp);
  int x0 = (int)f;
  float t = gp - f;
  int b = 0;
#pragma unroll
  for (int k = 0; k < 2; ++k) {
    int xc = x0 + k;
    float cw = k ? t : 1.0f - t;
    if (xc < 0 || xc >= n) cw = 0.0f;
    int xcc = min(max(xc, 0), n - 1);
    int u = half * n + xcc;
    float src = fmaxf((float)u * 0.5f - 0.25f, 0.0f);
    float sf = floorf(src);
    int i0 = (int)sf;
    float tu = src - sf;
    int i1 = min(i0 + 1, n - 1);
    if (k == 0) b = i0;
    int s0 = i0 - b;
    int s1 = i1 - b;
    float a0 = cw * (1.0f - tu);
    float a1 = cw * tu;
    w0 += (s0 == 0) ? a0 : 0.0f;
    w1 += (s0 == 1) ? a0 : 0.0f;
    w0 += (s1 == 0) ? a1 : 0.0f;
    w1 += (s1 == 1) ? a1 : 0.0f;
    w2 += (s1 == 2) ? a1 : 0.0f;
  }
  base = b;
  w0o = w0; w1o = w1; w2o = w2;
}

// ---------- Kernel A: 1x1 conv + geometry + NCHW->NHWC fp16 transpose ------
// geomC layout: per 32-pixel block, 32 dwords per pixel in [dword][px] order:
//   dword g*8+{0,1,2}=wx[3], {3,4,5}=wy[3]*mask, 6=rb(bits), 7=cb(bits)
__global__ __launch_bounds__(256) void prep_kernel(
    const float* __restrict__ x,
    const float* __restrict__ w_off, const float* __restrict__ b_off,
    const float* __restrict__ w_mask, const float* __restrict__ b_mask,
    __half* __restrict__ xT, float* __restrict__ geomC, int npix) {
  __shared__ float wt[CC * 12];
  __shared__ float tile[16][68];
  int t = threadIdx.x;
  for (int idx = t; idx < CC * 12; idx += 256) {
    int c = idx / 12, d = idx - c * 12;
    wt[idx] = (d < 8) ? w_off[d * CC + c] : w_mask[(d - 8) * CC + c];
  }
  __syncthreads();

  int pix0 = blockIdx.x * 256;
  int pix = pix0 + t;
  int b = pix >> 14;
  int ij = pix & (HWS - 1);
  int i = ij >> 7, j = ij & (WW - 1);
  const float* __restrict__ xp = x + (size_t)b * CC * HWS;

  float a12[12];
#pragma unroll
  for (int d = 0; d < 12; ++d) a12[d] = (d < 8) ? b_off[d] : b_mask[d - 8];
#pragma unroll 4
  for (int c = 0; c < CC; ++c) {
    float xv = xp[c * HWS + ij];
    const float4 w0 = *reinterpret_cast<const float4*>(&wt[c * 12 + 0]);
    const float4 w1 = *reinterpret_cast<const float4*>(&wt[c * 12 + 4]);
    const float4 w2 = *reinterpret_cast<const float4*>(&wt[c * 12 + 8]);
    a12[0]  = fmaf(w0.x, xv, a12[0]);   a12[1]  = fmaf(w0.y, xv, a12[1]);
    a12[2]  = fmaf(w0.z, xv, a12[2]);   a12[3]  = fmaf(w0.w, xv, a12[3]);
    a12[4]  = fmaf(w1.x, xv, a12[4]);   a12[5]  = fmaf(w1.y, xv, a12[5]);
    a12[6]  = fmaf(w1.z, xv, a12[6]);   a12[7]  = fmaf(w1.w, xv, a12[7]);
    a12[8]  = fmaf(w2.x, xv, a12[8]);   a12[9]  = fmaf(w2.y, xv, a12[9]);
    a12[10] = fmaf(w2.z, xv, a12[10]);  a12[11] = fmaf(w2.w, xv, a12[11]);
  }

  // compact geometry record (coalesced [dword][px] stores within 32-px block)
  float* __restrict__ gb = geomC + (size_t)(pix >> 5) * 1024 + (pix & 31);
#pragma unroll
  for (int g = 0; g < NG; ++g) {
    int sy = g >> 1, sx = g & 1;
    float mg = 1.0f / (1.0f + __expf(-a12[8 + g]));
    int cb, rb;
    float x0, x1, x2, y0, y1, y2;
    make_taps((float)j + a12[2 * g]     - 0.5f, WW, sx, cb, x0, x1, x2);
    make_taps((float)i + a12[2 * g + 1] - 0.5f, HH, sy, rb, y0, y1, y2);
    gb[(g * 8 + 0) * 32] = x0;
    gb[(g * 8 + 1) * 32] = x1;
    gb[(g * 8 + 2) * 32] = x2;
    gb[(g * 8 + 3) * 32] = y0 * mg;
    gb[(g * 8 + 4) * 32] = y1 * mg;
    gb[(g * 8 + 5) * 32] = y2 * mg;
    gb[(g * 8 + 6) * 32] = __int_as_float(rb);
    gb[(g * 8 + 7) * 32] = __int_as_float(cb);
  }

  // NCHW -> NHWC fp16 transpose, 16 chunks of (16 px x 64 ch)
  for (int ch = 0; ch < 16; ++ch) {
    int p0 = pix0 + ch * 16;
    int bb = p0 >> 14;
    int ij0 = p0 & (HWS - 1);
    const float* __restrict__ xq = x + (size_t)bb * CC * HWS + ij0;
    float v[4];
#pragma unroll
    for (int k = 0; k < 4; ++k) {
      int idx = k * 256 + t;
      int c = idx >> 4, p = idx & 15;
      v[k] = xq[c * HWS + p];
    }
    __syncthreads();
#pragma unroll
    for (int k = 0; k < 4; ++k) {
      int idx = k * 256 + t;
      int c = idx >> 4, p = idx & 15;
      tile[p][c] = v[k];
    }
    __syncthreads();
    float4 o = *reinterpret_cast<float4*>(&tile[t >> 4][(t & 15) * 4]);
    __half2 ha = __floats2half2_rn(o.x, o.y);
    __half2 hb = __floats2half2_rn(o.z, o.w);
    uint2 u;
    u.x = __builtin_bit_cast(unsigned int, ha);
    u.y = __builtin_bit_cast(unsigned int, hb);
    *reinterpret_cast<uint2*>(
        xT + ((size_t)p0 + (t >> 4)) * 64 + (t & 15) * 4) = u;
  }
}

// ---------- Kernel B: fp16 NHWC gather-sampler, precomputed geometry -------
__global__ __launch_bounds__(256) void sample16(
    const __half* __restrict__ xT, const float* __restrict__ geomC,
    float* __restrict__ out, int npix) {
  __shared__ float graw[1024];     // 32 px x 32 dwords, [dword][px]
  __shared__ int2 gexp[32][36];    // expanded (offset, weight) per px
  int t = threadIdx.x;

  int nwg = gridDim.x, bid = blockIdx.x;
  int swz = ((nwg & 7) == 0) ? ((bid & 7) * (nwg >> 3) + (bid >> 3)) : bid;

  // cooperative 4KB load of this block's compact geometry
  reinterpret_cast<uint4*>(graw)[t] =
      reinterpret_cast<const uint4*>(geomC + (size_t)swz * 1024)[t];
  __syncthreads();

  if (t < 128) {  // expand: thread (p,g) -> 9 (off,w) pairs
    int p = t >> 2, g = t & 3;
    float wx0 = graw[(g * 8 + 0) * 32 + p];
    float wx1 = graw[(g * 8 + 1) * 32 + p];
    float wx2 = graw[(g * 8 + 2) * 32 + p];
    float wy0 = graw[(g * 8 + 3) * 32 + p];
    float wy1 = graw[(g * 8 + 4) * 32 + p];
    float wy2 = graw[(g * 8 + 5) * 32 + p];
    int rb = __float_as_int(graw[(g * 8 + 6) * 32 + p]);
    int cb = __float_as_int(graw[(g * 8 + 7) * 32 + p]);
#pragma unroll
    for (int dy = 0; dy < 3; ++dy) {
      int ro = min(rb + dy, HH - 1) * WW;
      float wyv = (dy == 0) ? wy0 : ((dy == 1) ? wy1 : wy2);
#pragma unroll
      for (int dx = 0; dx < 3; ++dx) {
        int off = ro + min(cb + dx, WW - 1);
        float wv = wyv * ((dx == 0) ? wx0 : ((dx == 1) ? wx1 : wx2));
        gexp[p][g * 9 + dy * 3 + dx] = make_int2(off, __float_as_int(wv));
      }
    }
  }
  __syncthreads();

  int p = t >> 3, r = t & 7;       // 8 lanes per pixel, 8 channels per lane
  int pix = swz * 32 + p;
  int b = pix >> 14, ij = pix & (HWS - 1);
  const __half* __restrict__ xb = xT + ((size_t)b * HWS) * 64 + r * 8;

  float acc[8];
#pragma unroll
  for (int c = 0; c < 8; ++c) acc[c] = 0.0f;

#pragma unroll
  for (int k = 0; k < 36; ++k) {
    int2 ow = gexp[p][k];
    float w = __int_as_float(ow.y);
    uint4 v = *reinterpret_cast<const uint4*>(xb + (size_t)ow.x * 64);
    float2 f0 = __half22float2(__builtin_bit_cast(__half2, v.x));
    float2 f1 = __half22float2(__builtin_bit_cast(__half2, v.y));
    float2 f2 = __half22float2(__builtin_bit_cast(__half2, v.z));
    float2 f3 = __half22float2(__builtin_bit_cast(__half2, v.w));
    acc[0] = fmaf(w, f0.x, acc[0]);  acc[1] = fmaf(w, f0.y, acc[1]);
    acc[2] = fmaf(w, f1.x, acc[2]);  acc[3] = fmaf(w, f1.y, acc[3]);
    acc[4] = fmaf(w, f2.x, acc[4]);  acc[5] = fmaf(w, f2.y, acc[5]);
    acc[6] = fmaf(w, f3.x, acc[6]);  acc[7] = fmaf(w, f3.y, acc[7]);
  }

  float* __restrict__ op = out + ((size_t)b * CC + r * 8) * HWS + ij;
#pragma unroll
  for (int c = 0; c < 8; ++c) op[(size_t)c * HWS] = acc[c];
}

// ---------- Fallback: round-4 fused kernel (used if ws too small) ----------
__global__ __launch_bounds__(256) void dysample_fused(
    const float* __restrict__ x,
    const float* __restrict__ w_off, const float* __restrict__ b_off,
    const float* __restrict__ w_mask, const float* __restrict__ b_mask,
    float* __restrict__ out, int npix) {
  __shared__ float wt[CC * 12];
  for (int idx = threadIdx.x; idx < CC * 12; idx += 256) {
    int c = idx / 12, d = idx - c * 12;
    wt[idx] = (d < 8) ? w_off[d * CC + c] : w_mask[(d - 8) * CC + c];
  }
  __syncthreads();
  int nwg = gridDim.x;
  int bid = blockIdx.x;
  int swz = ((nwg & 7) == 0) ? ((bid & 7) * (nwg >> 3) + (bid >> 3)) : bid;
  int pix = swz * 256 + threadIdx.x;
  if (pix >= npix) return;
  int b = pix >> 14;
  int ij = pix & (HWS - 1);
  int i = ij >> 7, j = ij & (WW - 1);
  const float* __restrict__ xp = x + (size_t)b * CC * HWS;
  float a12[12];
#pragma unroll
  for (int d = 0; d < 12; ++d) a12[d] = (d < 8) ? b_off[d] : b_mask[d - 8];
#pragma unroll 4
  for (int c = 0; c < CC; ++c) {
    float xv = xp[c * HWS + ij];
    const float4 w0 = *reinterpret_cast<const float4*>(&wt[c * 12 + 0]);
    const float4 w1 = *reinterpret_cast<const float4*>(&wt[c * 12 + 4]);
    const float4 w2 = *reinterpret_cast<const float4*>(&wt[c * 12 + 8]);
    a12[0]  = fmaf(w0.x, xv, a12[0]);   a12[1]  = fmaf(w0.y, xv, a12[1]);
    a12[2]  = fmaf(w0.z, xv, a12[2]);   a12[3]  = fmaf(w0.w, xv, a12[3]);
    a12[4]  = fmaf(w1.x, xv, a12[4]);   a12[5]  = fmaf(w1.y, xv, a12[5]);
    a12[6]  = fmaf(w1.z, xv, a12[6]);   a12[7]  = fmaf(w1.w, xv, a12[7]);
    a12[8]  = fmaf(w2.x, xv, a12[8]);   a12[9]  = fmaf(w2.y, xv, a12[9]);
    a12[10] = fmaf(w2.z, xv, a12[10]);  a12[11] = fmaf(w2.w, xv, a12[11]);
  }
  int ro[NG][3], co[NG][3];
  float wx[NG][3], wy[NG][3];
#pragma unroll
  for (int g = 0; g < NG; ++g) {
    int sy = g >> 1, sx = g & 1;
    float mg = 1.0f / (1.0f + __expf(-a12[8 + g]));
    int cb, rb;
    float x0, x1, x2, y0, y1, y2;
    make_taps((float)j + a12[2 * g]     - 0.5f, WW, sx, cb, x0, x1, x2);
    make_taps((float)i + a12[2 * g + 1] - 0.5f, HH, sy, rb, y0, y1, y2);
    wx[g][0] = x0;      wx[g][1] = x1;      wx[g][2] = x2;
    wy[g][0] = y0 * mg; wy[g][1] = y1 * mg; wy[g][2] = y2 * mg;
#pragma unroll
    for (int d = 0; d < 3; ++d) {
      ro[g][d] = min(rb + d, HH - 1) * WW;
      co[g][d] = min(cb + d, WW - 1);
    }
  }
  float* __restrict__ op = out + (size_t)b * CC * HWS + ij;
  for (int blk = 0; blk < 4; ++blk) {
    const float* __restrict__ xb = xp + blk * 16 * HWS;
    float acc[16];
#pragma unroll
    for (int c = 0; c < 16; ++c) acc[c] = 0.0f;
#pragma unroll
    for (int g = 0; g < NG; ++g) {
      int o9[9];
      float w9[9];
#pragma unroll
      for (int dy = 0; dy < 3; ++dy) {
#pragma unroll
        for (int dx = 0; dx < 3; ++dx) {
          o9[dy * 3 + dx] = ro[g][dy] + co[g][dx];
          w9[dy * 3 + dx] = wy[g][dy] * wx[g][dx];
        }
      }
#pragma unroll
      for (int c = 0; c < 16; ++c) {
        const float* __restrict__ xc = xb + c * HWS;
#pragma unroll
        for (int k = 0; k < 9; ++k) acc[c] = fmaf(w9[k], xc[o9[k]], acc[c]);
      }
    }
#pragma unroll
    for (int c = 0; c < 16; ++c) op[(blk * 16 + c) * HWS] = acc[c];
  }
}

extern "C" void kernel_launch(void* const* d_in, const int* in_sizes, int n_in,
                              void* d_out, int out_size, void* d_ws, size_t ws_size,
                              hipStream_t stream) {
  const float* x      = (const float*)d_in[0];
  const float* w_off  = (const float*)d_in[1];
  const float* b_off  = (const float*)d_in[2];
  const float* w_mask = (const float*)d_in[3];
  const float* b_mask = (const float*)d_in[4];
  float* out = (float*)d_out;

  int B = in_sizes[0] / (CC * HWS);
  int npix = B * HWS;
  // xT (fp16, npix*64*2 B) + geomC (npix*128 B)
  size_t need = (size_t)npix * 128 + (size_t)npix * 128;

  if (ws_size >= need && (npix & 255) == 0) {
    __half* xT   = (__half*)d_ws;
    float* geomC = (float*)((char*)d_ws + (size_t)npix * 128);
    hipLaunchKernelGGL(prep_kernel, dim3(npix / 256), dim3(256), 0, stream,
                       x, w_off, b_off, w_mask, b_mask, xT, geomC, npix);
    hipLaunchKernelGGL(sample16, dim3(npix / 32), dim3(256), 0, stream,
                       xT, geomC, out, npix);
  } else {
    int nblk = (npix + 255) / 256;
    hipLaunchKernelGGL(dysample_fused, dim3(nblk), dim3(256), 0, stream,
                       x, w_off, b_off, w_mask, b_mask, out, npix);
  }
}